// Round 9
// baseline (352.568 us; speedup 1.0000x reference)
//
#include <hip/hip_runtime.h>
#include <hip/hip_bf16.h>
#include <stdint.h>

#define E_EDGES 500000
#define NNODES  50000
#define DN 128
#define DE 64
#define DH 256
#define DO 64
#define NWAVES (E_EDGES / 16)    // 31250 waves, 16 edges each

typedef __attribute__((ext_vector_type(8))) short short8;
typedef __attribute__((ext_vector_type(4))) short short4v;
typedef __attribute__((ext_vector_type(4))) float f32x4;

__device__ __forceinline__ short f2bf(float f) {
    union { __hip_bfloat16 h; short s; } u;
    u.h = __float2bfloat16(f);
    return u.s;
}
__device__ __forceinline__ uint32_t pack2bf(float a, float b) {
    return (uint32_t)(uint16_t)f2bf(a) | ((uint32_t)(uint16_t)f2bf(b) << 16);
}

// WcatT[512][128]: c<256 -> W1[k][c] (W1a^T), c>=256 -> W1[128+k][c-256] (W1b^T)
// W1cT [256][64] : W1[256+k][c] ; W2T [64][256] : W2[k][n]
__global__ void convert_weights(const float* __restrict__ W1, const float* __restrict__ W2,
                                short* __restrict__ WcatT, short* __restrict__ W1cT,
                                short* __restrict__ W2T) {
    int idx = blockIdx.x * 256 + threadIdx.x;
    if (idx < 512 * 128) {
        int c = idx >> 7, k = idx & 127;
        WcatT[idx] = f2bf(W1[(c < 256 ? k : k + 128) * DH + (c & 255)]);
    } else if (idx < 512 * 128 + 256 * 64) {
        int i = idx - 512 * 128;
        int c = i >> 6, k = i & 63;
        W1cT[i] = f2bf(W1[(256 + k) * DH + c]);
    } else if (idx < 512 * 128 + 256 * 64 + 64 * 256) {
        int i = idx - 512 * 128 - 256 * 64;
        int n = i >> 8, k = i & 255;
        W2T[i] = f2bf(W2[k * DO + n]);
    }
}

// PQ[50000][512] bf16 = [ nf@W1a + b1 | nf@W1b ]
__global__ __launch_bounds__(256, 4) void node_gemm(
    const float* __restrict__ nf, const short* __restrict__ WcatT,
    const float* __restrict__ b1, short* __restrict__ PQ)
{
    __shared__ __align__(16) short xt[64 * 128];   // [64][128] bf16, XOR-swizzled, 16KB
    const int tid = threadIdx.x, lane = tid & 63, wv = tid >> 6;
    const int lr = lane & 15, lk = lane >> 4;
    const int r0 = blockIdx.x * 64;
    const int cb = blockIdx.y * 256;
    char* xb = (char*)xt;

    {   // stage nf tile (rows clamped; garbage rows never stored)
        int r = tid >> 2, q = tid & 3;
        int gr = r0 + r; if (gr > NNODES - 1) gr = NNODES - 1;
        const float4* src = (const float4*)(nf + (long)gr * DN) + q * 8;
        #pragma unroll
        for (int i = 0; i < 4; ++i) {
            float4 a = src[2 * i], b = src[2 * i + 1];
            short8 s = { f2bf(a.x), f2bf(a.y), f2bf(a.z), f2bf(a.w),
                         f2bf(b.x), f2bf(b.y), f2bf(b.z), f2bf(b.w) };
            *(short8*)(xb + ((r * 256 + q * 64 + i * 16) ^ ((r & 7) << 4))) = s;
        }
    }
    __syncthreads();

    f32x4 acc[4][4];
    #pragma unroll
    for (int m = 0; m < 4; ++m)
        #pragma unroll
        for (int n = 0; n < 4; ++n)
            acc[m][n] = (f32x4){0.f, 0.f, 0.f, 0.f};

    #pragma unroll
    for (int kt = 0; kt < 4; ++kt) {
        short8 a[4], w[4];
        #pragma unroll
        for (int m = 0; m < 4; ++m) {
            int row = 16 * m + lr;
            a[m] = *(const short8*)(xb + ((row * 256 + kt * 64 + lk * 16) ^ ((row & 7) << 4)));
        }
        #pragma unroll
        for (int n = 0; n < 4; ++n)
            w[n] = *(const short8*)(WcatT + (long)(cb + wv * 64 + n * 16 + lr) * 128 + kt * 32 + lk * 8);
        #pragma unroll
        for (int m = 0; m < 4; ++m)
            #pragma unroll
            for (int n = 0; n < 4; ++n)
                acc[m][n] = __builtin_amdgcn_mfma_f32_16x16x32_bf16(w[n], a[m], acc[m][n], 0, 0, 0);
    }

    #pragma unroll
    for (int m = 0; m < 4; ++m) {
        int row = r0 + 16 * m + lr;
        if (row < NNODES) {
            #pragma unroll
            for (int n = 0; n < 4; ++n) {
                float4 bv = make_float4(0.f, 0.f, 0.f, 0.f);
                if (cb == 0) bv = *(const float4*)(b1 + wv * 64 + n * 16 + lk * 4);
                short4v s = { f2bf(acc[m][n][0] + bv.x), f2bf(acc[m][n][1] + bv.y),
                              f2bf(acc[m][n][2] + bv.z), f2bf(acc[m][n][3] + bv.w) };
                *(short4v*)(PQ + (long)row * 512 + cb + wv * 64 + n * 16 + lk * 4) = s;
            }
        }
    }
}

// One wave owns 16 edges end-to-end. No LDS, no barriers.
// h = relu(P[row]+Q[col]+ea@W1c)  [b1 folded into P]; out = h@W2+b2.
// Layer-1 D-frag -> GEMM2 B-frag repack: 8 shuffles (both n-groups), select
// AFTER the shuffle by the TARGET lane's a = lk>>1 (R8's bug: selected by source).
__global__ __launch_bounds__(256, 4) void edge_fused(
    const int* __restrict__ eidx, const float* __restrict__ ea,
    const short* __restrict__ PQ, const short* __restrict__ W1cT,
    const short* __restrict__ W2T, const float* __restrict__ b2,
    float* __restrict__ out)
{
    const int tid = threadIdx.x, lane = tid & 63;
    const int w = blockIdx.x * 4 + (tid >> 6);
    if (w >= NWAVES) return;                    // wave-uniform exit
    const int lr = lane & 15, lk = lane >> 4;
    const long e0 = (long)w * 16;

    // identity A-fragment [I16 | I16]
    short8 ifrag;
    #pragma unroll
    for (int i = 0; i < 8; ++i)
        ifrag[i] = (((8 * lk + i) & 15) == lr) ? (short)0x3F80 : (short)0;

    const int ri = eidx[e0 + lr];
    const int ci = eidx[E_EDGES + e0 + lr];

    // PQ fragment base: lk<2 half reads P[ri], lk>=2 half reads Q[ci]
    const short* pqb = (lk < 2) ? (PQ + (long)ri * 512 + 8 * (lk & 1))
                                : (PQ + (long)ci * 512 + 256 + 8 * (lk & 1));

    // ea B-fragments (k-slices of my edge's 64 attrs), reused across all n
    short8 eaf[2];
    {
        const float* eap = ea + (e0 + lr) * DE + 8 * lk;
        #pragma unroll
        for (int kt = 0; kt < 2; ++kt) {
            float4 x = *(const float4*)(eap + 32 * kt);
            float4 y = *(const float4*)(eap + 32 * kt + 4);
            eaf[kt] = (short8){ f2bf(x.x), f2bf(x.y), f2bf(x.z), f2bf(x.w),
                                f2bf(y.x), f2bf(y.y), f2bf(y.z), f2bf(y.w) };
        }
    }

    f32x4 acc2[4];
    #pragma unroll
    for (int n2 = 0; n2 < 4; ++n2) acc2[n2] = (f32x4){0.f, 0.f, 0.f, 0.f};

    const f32x4 zz = (f32x4){0.f, 0.f, 0.f, 0.f};
    const int sA = lr + 32 * (lk & 1);          // source lanes: lk_src = 2*(lk&1), +1
    const int sB = sA + 16;
    const bool hi = (lk >= 2);                  // target's a = lk>>1 selects n-group

    #pragma unroll
    for (int nt = 0; nt < 8; ++nt) {
        // ---- layer 1 for hcol groups n = 2nt, 2nt+1 ----
        uint2 h[2];
        #pragma unroll
        for (int p = 0; p < 2; ++p) {
            const int n = 2 * nt + p;
            short8 pq = *(const short8*)(pqb + 16 * n);
            f32x4 a = __builtin_amdgcn_mfma_f32_16x16x32_bf16(ifrag, pq, zz, 0, 0, 0);
            #pragma unroll
            for (int kt = 0; kt < 2; ++kt) {
                short8 w1 = *(const short8*)(W1cT + (16 * n + lr) * 64 + 32 * kt + 8 * lk);
                a = __builtin_amdgcn_mfma_f32_16x16x32_bf16(w1, eaf[kt], a, 0, 0, 0);
            }
            h[p].x = pack2bf(fmaxf(a[0], 0.f), fmaxf(a[1], 0.f));
            h[p].y = pack2bf(fmaxf(a[2], 0.f), fmaxf(a[3], 0.f));
        }

        // ---- repack D-frag -> B-frag: hb[i] = h[edge=lr][32nt + 8lk + i] ----
        // shuffle BOTH n-groups from both source lanes, select by target's a.
        int x0A = __shfl((int)h[0].x, sA), y0A = __shfl((int)h[0].y, sA);
        int x1A = __shfl((int)h[1].x, sA), y1A = __shfl((int)h[1].y, sA);
        int x0B = __shfl((int)h[0].x, sB), y0B = __shfl((int)h[0].y, sB);
        int x1B = __shfl((int)h[1].x, sB), y1B = __shfl((int)h[1].y, sB);
        union { int i[4]; short8 s; } hb;
        hb.i[0] = hi ? x1A : x0A;
        hb.i[1] = hi ? y1A : y0A;
        hb.i[2] = hi ? x1B : x0B;
        hb.i[3] = hi ? y1B : y0B;

        // ---- GEMM2 k-step nt ----
        #pragma unroll
        for (int n2 = 0; n2 < 4; ++n2) {
            short8 w2 = *(const short8*)(W2T + (16 * n2 + lr) * 256 + 32 * nt + 8 * lk);
            acc2[n2] = __builtin_amdgcn_mfma_f32_16x16x32_bf16(w2, hb.s, acc2[n2], 0, 0, 0);
        }
    }

    // ---- store: lane holds out[e0+lr][16n2 + 4lk .. +3] ----
    float* op = out + (e0 + lr) * DO;
    #pragma unroll
    for (int n2 = 0; n2 < 4; ++n2) {
        float4 bb = *(const float4*)(b2 + 16 * n2 + 4 * lk);
        float4 o;
        o.x = acc2[n2][0] + bb.x;
        o.y = acc2[n2][1] + bb.y;
        o.z = acc2[n2][2] + bb.z;
        o.w = acc2[n2][3] + bb.w;
        *(float4*)(op + 16 * n2 + 4 * lk) = o;
    }
}

extern "C" void kernel_launch(void* const* d_in, const int* in_sizes, int n_in,
                              void* d_out, int out_size, void* d_ws, size_t ws_size,
                              hipStream_t stream) {
    const float* node_feats = (const float*)d_in[0];
    const int*   eidx       = (const int*)d_in[1];
    const float* edge_attr  = (const float*)d_in[2];
    const float* W1         = (const float*)d_in[3];
    const float* b1         = (const float*)d_in[4];
    const float* W2         = (const float*)d_in[5];
    const float* b2         = (const float*)d_in[6];
    float* out = (float*)d_out;

    short* WcatT = (short*)d_ws;            // 512*128
    short* W1cT  = WcatT + 512 * 128;       // 256*64
    short* W2T   = W1cT + 256 * 64;         // 64*256
    short* PQ    = W2T + 64 * 256;          // 50000*512 bf16 (~51.2MB)

    convert_weights<<<384, 256, 0, stream>>>(W1, W2, WcatT, W1cT, W2T);
    node_gemm<<<dim3(782, 2), 256, 0, stream>>>(node_feats, WcatT, b1, PQ);
    edge_fused<<<(NWAVES + 3) / 4, 256, 0, stream>>>(eidx, edge_attr, PQ, W1cT, W2T, b2, out);
}

// Round 10
// 352.281 us; speedup vs baseline: 1.0008x; 1.0008x over previous
//
#include <hip/hip_runtime.h>
#include <hip/hip_bf16.h>
#include <stdint.h>

#define E_EDGES 500000
#define NNODES  50000
#define DN 128
#define DE 64
#define DH 256
#define DO 64
#define NWAVES (E_EDGES / 16)    // 31250 waves, 16 edges each

typedef __attribute__((ext_vector_type(8))) short short8;
typedef __attribute__((ext_vector_type(4))) short short4v;
typedef __attribute__((ext_vector_type(4))) float f32x4;

__device__ __forceinline__ short f2bf(float f) {
    union { __hip_bfloat16 h; short s; } u;
    u.h = __float2bfloat16(f);
    return u.s;
}
__device__ __forceinline__ uint32_t pack2bf(float a, float b) {
    return (uint32_t)(uint16_t)f2bf(a) | ((uint32_t)(uint16_t)f2bf(b) << 16);
}

// WcatT[512][128]: c<256 -> W1[k][c] (W1a^T), c>=256 -> W1[128+k][c-256] (W1b^T)
// W1cT [256][64] : W1[256+k][c] ; W2T [64][256] : W2[k][n]
__global__ void convert_weights(const float* __restrict__ W1, const float* __restrict__ W2,
                                short* __restrict__ WcatT, short* __restrict__ W1cT,
                                short* __restrict__ W2T) {
    int idx = blockIdx.x * 256 + threadIdx.x;
    if (idx < 512 * 128) {
        int c = idx >> 7, k = idx & 127;
        WcatT[idx] = f2bf(W1[(c < 256 ? k : k + 128) * DH + (c & 255)]);
    } else if (idx < 512 * 128 + 256 * 64) {
        int i = idx - 512 * 128;
        int c = i >> 6, k = i & 63;
        W1cT[i] = f2bf(W1[(256 + k) * DH + c]);
    } else if (idx < 512 * 128 + 256 * 64 + 64 * 256) {
        int i = idx - 512 * 128 - 256 * 64;
        int n = i >> 8, k = i & 255;
        W2T[i] = f2bf(W2[k * DO + n]);
    }
}

// PQ[50000][512] bf16 = [ nf@W1a + b1 | nf@W1b ]
__global__ __launch_bounds__(256, 4) void node_gemm(
    const float* __restrict__ nf, const short* __restrict__ WcatT,
    const float* __restrict__ b1, short* __restrict__ PQ)
{
    __shared__ __align__(16) short xt[64 * 128];   // [64][128] bf16, XOR-swizzled, 16KB
    const int tid = threadIdx.x, lane = tid & 63, wv = tid >> 6;
    const int lr = lane & 15, lk = lane >> 4;
    const int r0 = blockIdx.x * 64;
    const int cb = blockIdx.y * 256;
    char* xb = (char*)xt;

    {   // stage nf tile (rows clamped; garbage rows never stored)
        int r = tid >> 2, q = tid & 3;
        int gr = r0 + r; if (gr > NNODES - 1) gr = NNODES - 1;
        const float4* src = (const float4*)(nf + (long)gr * DN) + q * 8;
        #pragma unroll
        for (int i = 0; i < 4; ++i) {
            float4 a = src[2 * i], b = src[2 * i + 1];
            short8 s = { f2bf(a.x), f2bf(a.y), f2bf(a.z), f2bf(a.w),
                         f2bf(b.x), f2bf(b.y), f2bf(b.z), f2bf(b.w) };
            *(short8*)(xb + ((r * 256 + q * 64 + i * 16) ^ ((r & 7) << 4))) = s;
        }
    }
    __syncthreads();

    f32x4 acc[4][4];
    #pragma unroll
    for (int m = 0; m < 4; ++m)
        #pragma unroll
        for (int n = 0; n < 4; ++n)
            acc[m][n] = (f32x4){0.f, 0.f, 0.f, 0.f};

    #pragma unroll
    for (int kt = 0; kt < 4; ++kt) {
        short8 a[4], w[4];
        #pragma unroll
        for (int m = 0; m < 4; ++m) {
            int row = 16 * m + lr;
            a[m] = *(const short8*)(xb + ((row * 256 + kt * 64 + lk * 16) ^ ((row & 7) << 4)));
        }
        #pragma unroll
        for (int n = 0; n < 4; ++n)
            w[n] = *(const short8*)(WcatT + (long)(cb + wv * 64 + n * 16 + lr) * 128 + kt * 32 + lk * 8);
        #pragma unroll
        for (int m = 0; m < 4; ++m)
            #pragma unroll
            for (int n = 0; n < 4; ++n)
                acc[m][n] = __builtin_amdgcn_mfma_f32_16x16x32_bf16(w[n], a[m], acc[m][n], 0, 0, 0);
    }

    #pragma unroll
    for (int m = 0; m < 4; ++m) {
        int row = r0 + 16 * m + lr;
        if (row < NNODES) {
            #pragma unroll
            for (int n = 0; n < 4; ++n) {
                float4 bv = make_float4(0.f, 0.f, 0.f, 0.f);
                if (cb == 0) bv = *(const float4*)(b1 + wv * 64 + n * 16 + lk * 4);
                short4v s = { f2bf(acc[m][n][0] + bv.x), f2bf(acc[m][n][1] + bv.y),
                              f2bf(acc[m][n][2] + bv.z), f2bf(acc[m][n][3] + bv.w) };
                *(short4v*)(PQ + (long)row * 512 + cb + wv * 64 + n * 16 + lk * 4) = s;
            }
        }
    }
}

// One wave owns 16 edges end-to-end. No LDS, no barriers.
// h = relu(P[row]+Q[col]+ea@W1c)  [b1 folded into P]; out = h@W2+b2.
// ALL 16 PQ fragment loads hoisted into registers up front (max MLP);
// D-frag -> B-frag repack: 8 shuffles, select AFTER by target's lk>>1.
__global__ __launch_bounds__(256, 4) void edge_fused(
    const int* __restrict__ eidx, const float* __restrict__ ea,
    const short* __restrict__ PQ, const short* __restrict__ W1cT,
    const short* __restrict__ W2T, const float* __restrict__ b2,
    float* __restrict__ out)
{
    const int tid = threadIdx.x, lane = tid & 63;
    const int w = blockIdx.x * 4 + (tid >> 6);
    if (w >= NWAVES) return;                    // wave-uniform exit
    const int lr = lane & 15, lk = lane >> 4;
    const long e0 = (long)w * 16;

    const int ri = eidx[e0 + lr];
    const int ci = eidx[E_EDGES + e0 + lr];

    // PQ fragment base: lk<2 half reads P[ri], lk>=2 half reads Q[ci]
    const short* pqb = (lk < 2) ? (PQ + (long)ri * 512 + 8 * (lk & 1))
                                : (PQ + (long)ci * 512 + 256 + 8 * (lk & 1));

    // ---- hoist: all 16 PQ fragment loads issued before any compute ----
    short8 pqf[16];
    #pragma unroll
    for (int n = 0; n < 16; ++n)
        pqf[n] = *(const short8*)(pqb + 16 * n);

    // ea B-fragments (k-slices of my edge's 64 attrs), reused across all n
    short8 eaf[2];
    {
        const float* eap = ea + (e0 + lr) * DE + 8 * lk;
        #pragma unroll
        for (int kt = 0; kt < 2; ++kt) {
            float4 x = *(const float4*)(eap + 32 * kt);
            float4 y = *(const float4*)(eap + 32 * kt + 4);
            eaf[kt] = (short8){ f2bf(x.x), f2bf(x.y), f2bf(x.z), f2bf(x.w),
                                f2bf(y.x), f2bf(y.y), f2bf(y.z), f2bf(y.w) };
        }
    }

    // identity A-fragment [I16 | I16]
    short8 ifrag;
    #pragma unroll
    for (int i = 0; i < 8; ++i)
        ifrag[i] = (((8 * lk + i) & 15) == lr) ? (short)0x3F80 : (short)0;

    f32x4 acc2[4];
    #pragma unroll
    for (int n2 = 0; n2 < 4; ++n2) acc2[n2] = (f32x4){0.f, 0.f, 0.f, 0.f};

    const f32x4 zz = (f32x4){0.f, 0.f, 0.f, 0.f};
    const int sA = lr + 32 * (lk & 1);          // source lanes: lk_src = 2*(lk&1), +1
    const int sB = sA + 16;
    const bool hi = (lk >= 2);                  // target's a = lk>>1 selects n-group

    #pragma unroll
    for (int nt = 0; nt < 8; ++nt) {
        // ---- layer 1 for hcol groups n = 2nt, 2nt+1 ----
        uint2 h[2];
        #pragma unroll
        for (int p = 0; p < 2; ++p) {
            const int n = 2 * nt + p;
            f32x4 a = __builtin_amdgcn_mfma_f32_16x16x32_bf16(ifrag, pqf[n], zz, 0, 0, 0);
            #pragma unroll
            for (int kt = 0; kt < 2; ++kt) {
                short8 w1 = *(const short8*)(W1cT + (16 * n + lr) * 64 + 32 * kt + 8 * lk);
                a = __builtin_amdgcn_mfma_f32_16x16x32_bf16(w1, eaf[kt], a, 0, 0, 0);
            }
            h[p].x = pack2bf(fmaxf(a[0], 0.f), fmaxf(a[1], 0.f));
            h[p].y = pack2bf(fmaxf(a[2], 0.f), fmaxf(a[3], 0.f));
        }

        // ---- repack D-frag -> B-frag: hb[i] = h[edge=lr][32nt + 8lk + i] ----
        int x0A = __shfl((int)h[0].x, sA), y0A = __shfl((int)h[0].y, sA);
        int x1A = __shfl((int)h[1].x, sA), y1A = __shfl((int)h[1].y, sA);
        int x0B = __shfl((int)h[0].x, sB), y0B = __shfl((int)h[0].y, sB);
        int x1B = __shfl((int)h[1].x, sB), y1B = __shfl((int)h[1].y, sB);
        union { int i[4]; short8 s; } hb;
        hb.i[0] = hi ? x1A : x0A;
        hb.i[1] = hi ? y1A : y0A;
        hb.i[2] = hi ? x1B : x0B;
        hb.i[3] = hi ? y1B : y0B;

        // ---- GEMM2 k-step nt ----
        #pragma unroll
        for (int n2 = 0; n2 < 4; ++n2) {
            short8 w2 = *(const short8*)(W2T + (16 * n2 + lr) * 256 + 32 * nt + 8 * lk);
            acc2[n2] = __builtin_amdgcn_mfma_f32_16x16x32_bf16(w2, hb.s, acc2[n2], 0, 0, 0);
        }
    }

    // ---- store: lane holds out[e0+lr][16n2 + 4lk .. +3] ----
    float* op = out + (e0 + lr) * DO;
    #pragma unroll
    for (int n2 = 0; n2 < 4; ++n2) {
        float4 bb = *(const float4*)(b2 + 16 * n2 + 4 * lk);
        float4 o;
        o.x = acc2[n2][0] + bb.x;
        o.y = acc2[n2][1] + bb.y;
        o.z = acc2[n2][2] + bb.z;
        o.w = acc2[n2][3] + bb.w;
        *(float4*)(op + 16 * n2 + 4 * lk) = o;
    }
}

extern "C" void kernel_launch(void* const* d_in, const int* in_sizes, int n_in,
                              void* d_out, int out_size, void* d_ws, size_t ws_size,
                              hipStream_t stream) {
    const float* node_feats = (const float*)d_in[0];
    const int*   eidx       = (const int*)d_in[1];
    const float* edge_attr  = (const float*)d_in[2];
    const float* W1         = (const float*)d_in[3];
    const float* b1         = (const float*)d_in[4];
    const float* W2         = (const float*)d_in[5];
    const float* b2         = (const float*)d_in[6];
    float* out = (float*)d_out;

    short* WcatT = (short*)d_ws;            // 512*128
    short* W1cT  = WcatT + 512 * 128;       // 256*64
    short* W2T   = W1cT + 256 * 64;         // 64*256
    short* PQ    = W2T + 64 * 256;          // 50000*512 bf16 (~51.2MB)

    convert_weights<<<384, 256, 0, stream>>>(W1, W2, WcatT, W1cT, W2T);
    node_gemm<<<dim3(782, 2), 256, 0, stream>>>(node_feats, WcatT, b1, PQ);
    edge_fused<<<(NWAVES + 3) / 4, 256, 0, stream>>>(eidx, edge_attr, PQ, W1cT, W2T, b2, out);
}

// Round 11
// 350.190 us; speedup vs baseline: 1.0068x; 1.0060x over previous
//
#include <hip/hip_runtime.h>
#include <hip/hip_bf16.h>
#include <stdint.h>

#define E_EDGES 500000
#define NNODES  50000
#define DN 128
#define DE 64
#define DH 256
#define DO 64
#define NWAVES (E_EDGES / 16)    // 31250 waves, 16 edges each

typedef __attribute__((ext_vector_type(8))) short short8;
typedef __attribute__((ext_vector_type(4))) short short4v;
typedef __attribute__((ext_vector_type(4))) float f32x4;
typedef __attribute__((ext_vector_type(4))) int   i32x4;

__device__ __forceinline__ short f2bf(float f) {
    union { __hip_bfloat16 h; short s; } u;
    u.h = __float2bfloat16(f);
    return u.s;
}
__device__ __forceinline__ uint32_t pack2bf(float a, float b) {
    return (uint32_t)(uint16_t)f2bf(a) | ((uint32_t)(uint16_t)f2bf(b) << 16);
}

// WcatT[512][128]: c<256 -> W1[k][c] (W1a^T), c>=256 -> W1[128+k][c-256] (W1b^T)
// W1cT [256][64] : W1[256+k][c] ; W2T [64][256] : W2[k][n]
__global__ void convert_weights(const float* __restrict__ W1, const float* __restrict__ W2,
                                short* __restrict__ WcatT, short* __restrict__ W1cT,
                                short* __restrict__ W2T) {
    int idx = blockIdx.x * 256 + threadIdx.x;
    if (idx < 512 * 128) {
        int c = idx >> 7, k = idx & 127;
        WcatT[idx] = f2bf(W1[(c < 256 ? k : k + 128) * DH + (c & 255)]);
    } else if (idx < 512 * 128 + 256 * 64) {
        int i = idx - 512 * 128;
        int c = i >> 6, k = i & 63;
        W1cT[i] = f2bf(W1[(256 + k) * DH + c]);
    } else if (idx < 512 * 128 + 256 * 64 + 64 * 256) {
        int i = idx - 512 * 128 - 256 * 64;
        int n = i >> 8, k = i & 255;
        W2T[i] = f2bf(W2[k * DO + n]);
    }
}

// PQ[50000][512] bf16 = [ nf@W1a + b1 | nf@W1b ]
__global__ __launch_bounds__(256, 4) void node_gemm(
    const float* __restrict__ nf, const short* __restrict__ WcatT,
    const float* __restrict__ b1, short* __restrict__ PQ)
{
    __shared__ __align__(16) short xt[64 * 128];   // [64][128] bf16, XOR-swizzled, 16KB
    const int tid = threadIdx.x, lane = tid & 63, wv = tid >> 6;
    const int lr = lane & 15, lk = lane >> 4;
    const int r0 = blockIdx.x * 64;
    const int cb = blockIdx.y * 256;
    char* xb = (char*)xt;

    {   // stage nf tile (rows clamped; garbage rows never stored)
        int r = tid >> 2, q = tid & 3;
        int gr = r0 + r; if (gr > NNODES - 1) gr = NNODES - 1;
        const float4* src = (const float4*)(nf + (long)gr * DN) + q * 8;
        #pragma unroll
        for (int i = 0; i < 4; ++i) {
            float4 a = src[2 * i], b = src[2 * i + 1];
            short8 s = { f2bf(a.x), f2bf(a.y), f2bf(a.z), f2bf(a.w),
                         f2bf(b.x), f2bf(b.y), f2bf(b.z), f2bf(b.w) };
            *(short8*)(xb + ((r * 256 + q * 64 + i * 16) ^ ((r & 7) << 4))) = s;
        }
    }
    __syncthreads();

    f32x4 acc[4][4];
    #pragma unroll
    for (int m = 0; m < 4; ++m)
        #pragma unroll
        for (int n = 0; n < 4; ++n)
            acc[m][n] = (f32x4){0.f, 0.f, 0.f, 0.f};

    #pragma unroll
    for (int kt = 0; kt < 4; ++kt) {
        short8 a[4], w[4];
        #pragma unroll
        for (int m = 0; m < 4; ++m) {
            int row = 16 * m + lr;
            a[m] = *(const short8*)(xb + ((row * 256 + kt * 64 + lk * 16) ^ ((row & 7) << 4)));
        }
        #pragma unroll
        for (int n = 0; n < 4; ++n)
            w[n] = *(const short8*)(WcatT + (long)(cb + wv * 64 + n * 16 + lr) * 128 + kt * 32 + lk * 8);
        #pragma unroll
        for (int m = 0; m < 4; ++m)
            #pragma unroll
            for (int n = 0; n < 4; ++n)
                acc[m][n] = __builtin_amdgcn_mfma_f32_16x16x32_bf16(w[n], a[m], acc[m][n], 0, 0, 0);
    }

    #pragma unroll
    for (int m = 0; m < 4; ++m) {
        int row = r0 + 16 * m + lr;
        if (row < NNODES) {
            #pragma unroll
            for (int n = 0; n < 4; ++n) {
                float4 bv = make_float4(0.f, 0.f, 0.f, 0.f);
                if (cb == 0) bv = *(const float4*)(b1 + wv * 64 + n * 16 + lk * 4);
                short4v s = { f2bf(acc[m][n][0] + bv.x), f2bf(acc[m][n][1] + bv.y),
                              f2bf(acc[m][n][2] + bv.z), f2bf(acc[m][n][3] + bv.w) };
                *(short4v*)(PQ + (long)row * 512 + cb + wv * 64 + n * 16 + lk * 4) = s;
            }
        }
    }
}

// One wave owns 16 edges end-to-end. No LDS tiles, no barriers.
// All 20 gather loads issued via inline asm (pinned, concurrent in flight),
// single vmcnt(0) drain + sched_barrier before consumption (rule #18).
__global__ __launch_bounds__(256, 3) void edge_fused(
    const int* __restrict__ eidx, const float* __restrict__ ea,
    const short* __restrict__ PQ, const short* __restrict__ W1cT,
    const short* __restrict__ W2T, const float* __restrict__ b2,
    float* __restrict__ out)
{
    const int tid = threadIdx.x, lane = tid & 63;
    const int w = blockIdx.x * 4 + (tid >> 6);
    if (w >= NWAVES) return;                    // wave-uniform exit
    const int lr = lane & 15, lk = lane >> 4;
    const long e0 = (long)w * 16;

    const int ri = eidx[e0 + lr];
    const int ci = eidx[E_EDGES + e0 + lr];

    // PQ fragment base: lk<2 half reads P[ri], lk>=2 half reads Q[ci]
    const short* pqb = (lk < 2) ? (PQ + (long)ri * 512 + 8 * (lk & 1))
                                : (PQ + (long)ci * 512 + 256 + 8 * (lk & 1));
    const float* eap = ea + (e0 + lr) * DE + 8 * lk;

    // ---- issue ALL gather loads back-to-back; results pinned in VGPRs ----
    i32x4 eraw[4];                               // ea: 2 kt x 2 float4
    #pragma unroll
    for (int kt = 0; kt < 2; ++kt) {
        asm volatile("global_load_dwordx4 %0, %1, off"
                     : "=v"(eraw[2 * kt])     : "v"(eap + 32 * kt));
        asm volatile("global_load_dwordx4 %0, %1, off"
                     : "=v"(eraw[2 * kt + 1]) : "v"(eap + 32 * kt + 4));
    }
    i32x4 pqf[16];                               // 16 PQ fragments, 16B each
    #pragma unroll
    for (int n = 0; n < 16; ++n)
        asm volatile("global_load_dwordx4 %0, %1, off"
                     : "=v"(pqf[n]) : "v"(pqb + 16 * n));

    // identity A-fragment [I16 | I16] (VALU work during load flight)
    short8 ifrag;
    #pragma unroll
    for (int i = 0; i < 8; ++i)
        ifrag[i] = (((8 * lk + i) & 15) == lr) ? (short)0x3F80 : (short)0;

    f32x4 acc2[4];
    #pragma unroll
    for (int n2 = 0; n2 < 4; ++n2) acc2[n2] = (f32x4){0.f, 0.f, 0.f, 0.f};

    // ---- drain all gathers, fence the scheduler ----
    asm volatile("s_waitcnt vmcnt(0)" ::: "memory");
    __builtin_amdgcn_sched_barrier(0);

    // ea -> bf16 B-fragments
    short8 eaf[2];
    #pragma unroll
    for (int kt = 0; kt < 2; ++kt) {
        union { i32x4 i; float4 f; } x, y;
        x.i = eraw[2 * kt]; y.i = eraw[2 * kt + 1];
        eaf[kt] = (short8){ f2bf(x.f.x), f2bf(x.f.y), f2bf(x.f.z), f2bf(x.f.w),
                            f2bf(y.f.x), f2bf(y.f.y), f2bf(y.f.z), f2bf(y.f.w) };
    }

    const f32x4 zz = (f32x4){0.f, 0.f, 0.f, 0.f};
    const int sA = lr + 32 * (lk & 1);          // source lanes: lk_src = 2*(lk&1), +1
    const int sB = sA + 16;
    const bool hi = (lk >= 2);                  // target's a = lk>>1 selects n-group

    #pragma unroll
    for (int nt = 0; nt < 8; ++nt) {
        // ---- layer 1 for hcol groups n = 2nt, 2nt+1 ----
        uint2 h[2];
        #pragma unroll
        for (int p = 0; p < 2; ++p) {
            const int n = 2 * nt + p;
            union { i32x4 i; short8 s; } pq; pq.i = pqf[n];
            f32x4 a = __builtin_amdgcn_mfma_f32_16x16x32_bf16(ifrag, pq.s, zz, 0, 0, 0);
            #pragma unroll
            for (int kt = 0; kt < 2; ++kt) {
                short8 w1 = *(const short8*)(W1cT + (16 * n + lr) * 64 + 32 * kt + 8 * lk);
                a = __builtin_amdgcn_mfma_f32_16x16x32_bf16(w1, eaf[kt], a, 0, 0, 0);
            }
            h[p].x = pack2bf(fmaxf(a[0], 0.f), fmaxf(a[1], 0.f));
            h[p].y = pack2bf(fmaxf(a[2], 0.f), fmaxf(a[3], 0.f));
        }

        // ---- repack D-frag -> B-frag: hb[i] = h[edge=lr][32nt + 8lk + i] ----
        int x0A = __shfl((int)h[0].x, sA), y0A = __shfl((int)h[0].y, sA);
        int x1A = __shfl((int)h[1].x, sA), y1A = __shfl((int)h[1].y, sA);
        int x0B = __shfl((int)h[0].x, sB), y0B = __shfl((int)h[0].y, sB);
        int x1B = __shfl((int)h[1].x, sB), y1B = __shfl((int)h[1].y, sB);
        union { int i[4]; short8 s; } hb;
        hb.i[0] = hi ? x1A : x0A;
        hb.i[1] = hi ? y1A : y0A;
        hb.i[2] = hi ? x1B : x0B;
        hb.i[3] = hi ? y1B : y0B;

        // ---- GEMM2 k-step nt ----
        #pragma unroll
        for (int n2 = 0; n2 < 4; ++n2) {
            short8 w2 = *(const short8*)(W2T + (16 * n2 + lr) * 256 + 32 * nt + 8 * lk);
            acc2[n2] = __builtin_amdgcn_mfma_f32_16x16x32_bf16(w2, hb.s, acc2[n2], 0, 0, 0);
        }
    }

    // ---- store: lane holds out[e0+lr][16n2 + 4lk .. +3] ----
    float* op = out + (e0 + lr) * DO;
    #pragma unroll
    for (int n2 = 0; n2 < 4; ++n2) {
        float4 bb = *(const float4*)(b2 + 16 * n2 + 4 * lk);
        float4 o;
        o.x = acc2[n2][0] + bb.x;
        o.y = acc2[n2][1] + bb.y;
        o.z = acc2[n2][2] + bb.z;
        o.w = acc2[n2][3] + bb.w;
        *(float4*)(op + 16 * n2 + 4 * lk) = o;
    }
}

extern "C" void kernel_launch(void* const* d_in, const int* in_sizes, int n_in,
                              void* d_out, int out_size, void* d_ws, size_t ws_size,
                              hipStream_t stream) {
    const float* node_feats = (const float*)d_in[0];
    const int*   eidx       = (const int*)d_in[1];
    const float* edge_attr  = (const float*)d_in[2];
    const float* W1         = (const float*)d_in[3];
    const float* b1         = (const float*)d_in[4];
    const float* W2         = (const float*)d_in[5];
    const float* b2         = (const float*)d_in[6];
    float* out = (float*)d_out;

    short* WcatT = (short*)d_ws;            // 512*128
    short* W1cT  = WcatT + 512 * 128;       // 256*64
    short* W2T   = W1cT + 256 * 64;         // 64*256
    short* PQ    = W2T + 64 * 256;          // 50000*512 bf16 (~51.2MB)

    convert_weights<<<384, 256, 0, stream>>>(W1, W2, WcatT, W1cT, W2T);
    node_gemm<<<dim3(782, 2), 256, 0, stream>>>(node_feats, WcatT, b1, PQ);
    edge_fused<<<(NWAVES + 3) / 4, 256, 0, stream>>>(eidx, edge_attr, PQ, W1cT, W2T, b2, out);
}